// Round 5
// baseline (102.758 us; speedup 1.0000x reference)
//
#include <hip/hip_runtime.h>

#define NDOCS 64
#define NPASS 1024
#define TITLE_LEN 128
#define SEQ 256
#define NEDGES 32768
#define NNODES 2112   // NDOCS + 2*NPASS
#define DIM 768
#define KA 2304       // 3*DIM fused K
#define NPAD 2176     // 34 * 64
#define SPAN_TOK 30522
#define NREL 2
#define NBINS (NREL * NNODES)  // 4224
#define BK 64
#define SPAN0 (NNODES - NPASS)  // 1088

typedef unsigned short u16;
typedef u16 u16x4 __attribute__((ext_vector_type(4)));
typedef __bf16 bf16x8 __attribute__((ext_vector_type(8)));
typedef float f32x4 __attribute__((ext_vector_type(4)));

__device__ inline u16 f2bf(float f) {
  unsigned u = __builtin_bit_cast(unsigned, f);
  u += 0x7FFFu + ((u >> 16) & 1u);
  return (u16)(u >> 16);
}
__device__ inline float bf2f(u16 h) {
  unsigned u = ((unsigned)h) << 16;
  return __builtin_bit_cast(float, u);
}
__device__ inline void gld16(const void* g, void* l) {
  __builtin_amdgcn_global_load_lds(
      (const __attribute__((address_space(1))) void*)g,
      (__attribute__((address_space(3))) void*)l, 16, 0, 0);
}

// ---------- CSR build in ONE block: hist -> scan -> scatter (LDS-resident) ----
__global__ __launch_bounds__(1024) void csr_kernel(
    const int* __restrict__ srcv, const int* __restrict__ dst,
    const int* __restrict__ et, int* __restrict__ offs, int* __restrict__ perm) {
  __shared__ int ldeg[NBINS];   // deg, then reused as cur
  __shared__ int part[1024];
  int t = threadIdx.x;
  for (int i = t; i < NBINS; i += 1024) ldeg[i] = 0;
  __syncthreads();
  for (int e = t; e < NEDGES; e += 1024)
    atomicAdd(&ldeg[et[e] * NNODES + dst[e]], 1);
  __syncthreads();
  // exclusive scan of ldeg into offs; 5 bins per thread
  int loc[5];
  int s = 0;
#pragma unroll
  for (int i = 0; i < 5; ++i) {
    int idx = t * 5 + i;
    loc[i] = s;
    s += (idx < NBINS) ? ldeg[idx] : 0;
  }
  part[t] = s;
  __syncthreads();
  for (int off = 1; off < 1024; off <<= 1) {
    int v = (t >= off) ? part[t - off] : 0;
    __syncthreads();
    part[t] += v;
    __syncthreads();
  }
  int pre = (t == 0) ? 0 : part[t - 1];
#pragma unroll
  for (int i = 0; i < 5; ++i) {
    int idx = t * 5 + i;
    if (idx < NBINS) {
      int val = pre + loc[i];
      offs[idx] = val;
      ldeg[idx] = val;  // becomes cur (safe: all scan reads completed pre-barrier)
    }
  }
  if (t == 1023) offs[NBINS] = part[1023];
  __syncthreads();
  for (int e = t; e < NEDGES; e += 1024) {
    int bin = et[e] * NNODES + dst[e];
    int p = atomicAdd(&ldeg[bin], 1);
    perm[p] = srcv[e];
  }
}

// ---------- fused prep: build_x | conv_bt | foldv (independent jobs) ----------
// blocks [0,2112): x rows; [2112,3840): Bt 32x32 tiles; [3840,4417): v rows
__global__ __launch_bounds__(256) void prep_kernel(
    const int* __restrict__ doc_ids, const int* __restrict__ pass_ids,
    const float* __restrict__ embed, const float* __restrict__ w_root1,
    const float* __restrict__ w_rel1, const float* __restrict__ w_root2,
    const float* __restrict__ w_rel2, const float* __restrict__ b2,
    const float* __restrict__ clf_w, const float* __restrict__ clf_b,
    u16* __restrict__ A1, u16* __restrict__ Bt, float* __restrict__ v) {
  __shared__ float tile[32][33];
  int b = blockIdx.x;
  int tid = threadIdx.x;
  if (b < NNODES) {  // ---- build_x ----
    if (tid < 192) {
      int tok;
      if (b < NDOCS) tok = doc_ids[b * TITLE_LEN];
      else if (b < NDOCS + NPASS) tok = pass_ids[(b - NDOCS) * SEQ];
      else tok = SPAN_TOK;
      float4 e = *reinterpret_cast<const float4*>(&embed[(size_t)tok * DIM + tid * 4]);
      u16x4 o;
      o.x = f2bf(e.x); o.y = f2bf(e.y); o.z = f2bf(e.z); o.w = f2bf(e.w);
      *reinterpret_cast<u16x4*>(&A1[(size_t)b * KA + tid * 4]) = o;
    }
  } else if (b < NNODES + (KA / 32) * (DIM / 32)) {  // ---- conv_bt ----
    int cb = b - NNODES;
    int k0 = (cb % (KA / 32)) * 32, n0 = (cb / (KA / 32)) * 32;
    int tx = tid & 31, ty = tid >> 5;  // 32 x 8
#pragma unroll
    for (int i = 0; i < 4; ++i) {
      int k = k0 + ty + 8 * i;
      const float* row = (k < DIM) ? (w_root1 + (size_t)k * DIM)
                                   : (w_rel1 + (size_t)(k - DIM) * DIM);
      tile[ty + 8 * i][tx] = row[n0 + tx];
    }
    __syncthreads();
#pragma unroll
    for (int i = 0; i < 4; ++i) {
      int n = n0 + ty + 8 * i;
      Bt[(size_t)n * KA + k0 + tx] = f2bf(tile[tx][ty + 8 * i]);
    }
  } else {  // ---- foldv: v[k] = row_k(Wcat2) . clf_w ; v[2304] = b2.clf_w + c0 --
    int fb = b - NNODES - (KA / 32) * (DIM / 32);
    int lane = tid & 63, wid = tid >> 6;
    int k = fb * 4 + wid;
    if (k <= 3 * DIM) {
      const float* row;
      if (k < DIM) row = w_root2 + (size_t)k * DIM;
      else if (k < 3 * DIM) row = w_rel2 + (size_t)(k - DIM) * DIM;
      else row = b2;
      float s = 0.f;
      for (int j = lane; j < DIM; j += 64) s += row[j] * clf_w[j];
#pragma unroll
      for (int off = 32; off > 0; off >>= 1) s += __shfl_down(s, off);
      if (lane == 0) v[k] = s + (k == 3 * DIM ? clf_b[0] : 0.f);
    }
  }
}

// ---------- per-bin mean gather (layer 1): writes A1 num-slices ----------
__global__ __launch_bounds__(192) void gather_kernel(const u16* __restrict__ A,
                                                     const int* __restrict__ offs,
                                                     const int* __restrict__ perm,
                                                     u16* __restrict__ Anum) {
  int bin = blockIdx.x;  // r*NNODES + d
  int r = bin / NNODES;
  int d = bin - r * NNODES;
  int beg = offs[bin], end = offs[bin + 1];
  int t = threadIdx.x;
  float a0 = 0.f, a1 = 0.f, a2 = 0.f, a3 = 0.f;
  for (int i = beg; i < end; ++i) {
    int s = perm[i];
    u16x4 v = *reinterpret_cast<const u16x4*>(&A[(size_t)s * KA + t * 4]);
    a0 += bf2f(v.x); a1 += bf2f(v.y); a2 += bf2f(v.z); a3 += bf2f(v.w);
  }
  float inv = (end > beg) ? 1.0f / (float)(end - beg) : 0.0f;
  u16x4 o;
  o.x = f2bf(a0 * inv); o.y = f2bf(a1 * inv); o.z = f2bf(a2 * inv); o.w = f2bf(a3 * inv);
  *reinterpret_cast<u16x4*>(&Anum[(size_t)d * KA + DIM + (size_t)r * DIM + t * 4]) = o;
}

// ---------- bf16 MFMA GEMM: out1[NPAD x 768] = A[NPAD x 2304] @ Bt^T + bias ----
// 64x64 tile, BK=64, 4 waves (2x2, 32x32 each), double-buffered LDS, 2-phase
// prefetch, XCD-swizzled 1D grid of 408. C is compact: ldc = DIM.
__global__ __launch_bounds__(256) void gemm_kernel(
    const u16* __restrict__ A, const u16* __restrict__ Bt,
    const float* __restrict__ bias, u16* __restrict__ C /* ldc = DIM */) {
  __shared__ u16 As[2][64 * BK];
  __shared__ u16 Bs[2][64 * BK];
  int wg = blockIdx.x;                  // 0..407, 408 = 8 XCDs * 51
  int swz = (wg & 7) * 51 + (wg >> 3);  // bijective: contiguous tiles per XCD
  int bm = swz / 12, bn = swz % 12;     // 34 x 12 tile grid
  int row0 = bm * 64, col0 = bn * 64;
  int tid = threadIdx.x;
  int lane = tid & 63, wid = tid >> 6;
  int wr = wid >> 1, wc = wid & 1;
  int l15 = lane & 15, l4 = lane >> 4;
  int sr = tid >> 3;  // staging row within 32-row chunk
  int sc = tid & 7;   // staging 16B slot
  f32x4 acc[2][2] = {};

#define STAGE(b, kbase)                                                         \
  {                                                                             \
    _Pragma("unroll") for (int h = 0; h < 2; ++h) {                             \
      int r = h * 32 + sr;                                                      \
      int kk = (sc ^ (r & 7)) * 8; /* pre-swizzled global source (rule #21) */  \
      gld16(&A[(size_t)(row0 + r) * KA + (kbase) + kk],                         \
            &As[b][h * 2048 + tid * 8]);                                        \
      gld16(&Bt[(size_t)(col0 + r) * KA + (kbase) + kk],                        \
            &Bs[b][h * 2048 + tid * 8]);                                        \
    }                                                                           \
  }

  STAGE(0, 0);
  __syncthreads();

  const int nt = KA / BK;  // 36
  for (int t = 0; t < nt; ++t) {
    int buf = t & 1;
    if (t + 1 < nt) STAGE(buf ^ 1, (t + 1) * BK);
    bf16x8 af[2][2], bg[2][2];
#pragma unroll
    for (int h = 0; h < 2; ++h) {
#pragma unroll
      for (int m = 0; m < 2; ++m) {
        int rl = wr * 32 + m * 16 + l15;
        int ck = (h * 4 + l4) ^ (rl & 7);
        af[h][m] = *reinterpret_cast<const bf16x8*>(&As[buf][rl * BK + ck * 8]);
        int cl = wc * 32 + m * 16 + l15;
        int ck2 = (h * 4 + l4) ^ (cl & 7);
        bg[h][m] = *reinterpret_cast<const bf16x8*>(&Bs[buf][cl * BK + ck2 * 8]);
      }
    }
#pragma unroll
    for (int h = 0; h < 2; ++h)
#pragma unroll
      for (int m = 0; m < 2; ++m)
#pragma unroll
        for (int n = 0; n < 2; ++n)
          acc[m][n] = __builtin_amdgcn_mfma_f32_16x16x32_bf16(af[h][m], bg[h][n],
                                                              acc[m][n], 0, 0, 0);
    __syncthreads();
  }
#undef STAGE

#pragma unroll
  for (int m = 0; m < 2; ++m) {
#pragma unroll
    for (int n = 0; n < 2; ++n) {
      int col = col0 + wc * 32 + n * 16 + l15;
      float b = bias[col];
#pragma unroll
      for (int q = 0; q < 4; ++q) {
        int row = row0 + wr * 32 + m * 16 + l4 * 4 + q;
        C[(size_t)row * DIM + col] = f2bf(acc[m][n][q] + b);
      }
    }
  }
}

// ---------- fused layer-2 + classifier for span rows ----------
// z = out1_span . v_root + sum_r mean(out1[src in bin r]) . v_r + c0
__global__ __launch_bounds__(192) void span_kernel(
    const u16* __restrict__ out1, const int* __restrict__ offs,
    const int* __restrict__ perm, const float* __restrict__ v,
    float* __restrict__ out) {
  int i = blockIdx.x;  // span idx 0..NPASS-1
  int t = threadIdx.x;
  // root path
  u16x4 a = *reinterpret_cast<const u16x4*>(&out1[(size_t)(SPAN0 + i) * DIM + t * 4]);
  float4 w = *reinterpret_cast<const float4*>(&v[t * 4]);
  float s = bf2f(a.x) * w.x + bf2f(a.y) * w.y + bf2f(a.z) * w.z + bf2f(a.w) * w.w;
  // relation paths
#pragma unroll
  for (int r = 0; r < NREL; ++r) {
    int bin = r * NNODES + SPAN0 + i;
    int beg = offs[bin], end = offs[bin + 1];
    if (end > beg) {
      float a0 = 0.f, a1 = 0.f, a2 = 0.f, a3 = 0.f;
      for (int e = beg; e < end; ++e) {
        int sr = perm[e];
        u16x4 x = *reinterpret_cast<const u16x4*>(&out1[(size_t)sr * DIM + t * 4]);
        a0 += bf2f(x.x); a1 += bf2f(x.y); a2 += bf2f(x.z); a3 += bf2f(x.w);
      }
      float4 wr = *reinterpret_cast<const float4*>(&v[DIM + r * DIM + t * 4]);
      s += (a0 * wr.x + a1 * wr.y + a2 * wr.z + a3 * wr.w) / (float)(end - beg);
    }
  }
#pragma unroll
  for (int off = 32; off > 0; off >>= 1) s += __shfl_down(s, off);
  __shared__ float red[3];
  if ((t & 63) == 0) red[t >> 6] = s;
  __syncthreads();
  if (t == 0) {
    float z = red[0] + red[1] + red[2] + v[3 * DIM];
    float sc = 1.0f / (1.0f + expf(-z));
    out[i] = expf(sc * 5.0f);  // exp(score / TAU), TAU = 0.2
  }
}

extern "C" void kernel_launch(void* const* d_in, const int* in_sizes, int n_in,
                              void* d_out, int out_size, void* d_ws, size_t ws_size,
                              hipStream_t stream) {
  const int* doc_ids = (const int*)d_in[0];
  const int* pass_ids = (const int*)d_in[1];
  const int* edge_index = (const int*)d_in[2];
  const int* etype = (const int*)d_in[3];
  const float* embed = (const float*)d_in[4];
  const float* w_root1 = (const float*)d_in[5];
  const float* w_rel1 = (const float*)d_in[6];
  const float* b1 = (const float*)d_in[7];
  const float* w_root2 = (const float*)d_in[8];
  const float* w_rel2 = (const float*)d_in[9];
  const float* b2 = (const float*)d_in[10];
  const float* clf_w = (const float*)d_in[11];
  const float* clf_b = (const float*)d_in[12];
  float* out = (float*)d_out;

  const int* src = edge_index;
  const int* dst = edge_index + NEDGES;

  u16* A1 = (u16*)d_ws;                        // NPAD * KA bf16
  u16* out1 = A1 + (size_t)NPAD * KA;          // NPAD * DIM bf16
  u16* Bt = out1 + (size_t)NPAD * DIM;         // DIM * KA bf16
  float* v = (float*)(Bt + (size_t)DIM * KA);  // 3*DIM + 1
  int* offs = (int*)(v + 3 * DIM + 1);         // NBINS + 1
  int* perm = offs + NBINS + 1;                // NEDGES

  csr_kernel<<<1, 1024, 0, stream>>>(src, dst, etype, offs, perm);
  prep_kernel<<<NNODES + (KA / 32) * (DIM / 32) + (3 * DIM + 4) / 4, 256, 0,
                stream>>>(doc_ids, pass_ids, embed, w_root1, w_rel1, w_root2,
                          w_rel2, b2, clf_w, clf_b, A1, Bt, v);
  gather_kernel<<<NBINS, 192, 0, stream>>>(A1, offs, perm, A1);
  gemm_kernel<<<408, 256, 0, stream>>>(A1, Bt, b1, out1);
  span_kernel<<<NPASS, 192, 0, stream>>>(out1, offs, perm, v, out);
}

// Round 6
// 70.863 us; speedup vs baseline: 1.4501x; 1.4501x over previous
//
#include <hip/hip_runtime.h>

#define NDOCS 64
#define NPASS 1024
#define TITLE_LEN 128
#define SEQ 256
#define NEDGES 32768
#define NNODES 2112   // NDOCS + 2*NPASS
#define DIM 768
#define KA 2304       // 3*DIM fused K
#define NPAD 2176     // 34 * 64
#define SPAN_TOK 30522
#define NREL 2
#define NBINS (NREL * NNODES)  // 4224
#define BK 64
#define SPAN0 (NNODES - NPASS)  // 1088

typedef unsigned short u16;
typedef u16 u16x4 __attribute__((ext_vector_type(4)));
typedef __bf16 bf16x8 __attribute__((ext_vector_type(8)));
typedef float f32x4 __attribute__((ext_vector_type(4)));

__device__ inline u16 f2bf(float f) {
  unsigned u = __builtin_bit_cast(unsigned, f);
  u += 0x7FFFu + ((u >> 16) & 1u);
  return (u16)(u >> 16);
}
__device__ inline float bf2f(u16 h) {
  unsigned u = ((unsigned)h) << 16;
  return __builtin_bit_cast(float, u);
}
__device__ inline void gld16(const void* g, void* l) {
  __builtin_amdgcn_global_load_lds(
      (const __attribute__((address_space(1))) void*)g,
      (__attribute__((address_space(3))) void*)l, 16, 0, 0);
}

// ---------- fused prep: build_x | conv_bt | foldv | clear-deg ----------
// blocks [0,2112): x rows; [2112,3840): Bt tiles; [3840,4417): v rows;
// [4417,4434): zero deg
__global__ __launch_bounds__(256) void prep_kernel(
    const int* __restrict__ doc_ids, const int* __restrict__ pass_ids,
    const float* __restrict__ embed, const float* __restrict__ w_root1,
    const float* __restrict__ w_rel1, const float* __restrict__ w_root2,
    const float* __restrict__ w_rel2, const float* __restrict__ b2,
    const float* __restrict__ clf_w, const float* __restrict__ clf_b,
    u16* __restrict__ A1, u16* __restrict__ Bt, float* __restrict__ v,
    int* __restrict__ deg) {
  __shared__ float tile[32][33];
  int b = blockIdx.x;
  int tid = threadIdx.x;
  if (b < NNODES) {  // ---- build_x ----
    if (tid < 192) {
      int tok;
      if (b < NDOCS) tok = doc_ids[b * TITLE_LEN];
      else if (b < NDOCS + NPASS) tok = pass_ids[(b - NDOCS) * SEQ];
      else tok = SPAN_TOK;
      float4 e = *reinterpret_cast<const float4*>(&embed[(size_t)tok * DIM + tid * 4]);
      u16x4 o;
      o.x = f2bf(e.x); o.y = f2bf(e.y); o.z = f2bf(e.z); o.w = f2bf(e.w);
      *reinterpret_cast<u16x4*>(&A1[(size_t)b * KA + tid * 4]) = o;
    }
  } else if (b < NNODES + (KA / 32) * (DIM / 32)) {  // ---- conv_bt ----
    int cb = b - NNODES;
    int k0 = (cb % (KA / 32)) * 32, n0 = (cb / (KA / 32)) * 32;
    int tx = tid & 31, ty = tid >> 5;  // 32 x 8
#pragma unroll
    for (int i = 0; i < 4; ++i) {
      int k = k0 + ty + 8 * i;
      const float* row = (k < DIM) ? (w_root1 + (size_t)k * DIM)
                                   : (w_rel1 + (size_t)(k - DIM) * DIM);
      tile[ty + 8 * i][tx] = row[n0 + tx];
    }
    __syncthreads();
#pragma unroll
    for (int i = 0; i < 4; ++i) {
      int n = n0 + ty + 8 * i;
      Bt[(size_t)n * KA + k0 + tx] = f2bf(tile[tx][ty + 8 * i]);
    }
  } else if (b < NNODES + (KA / 32) * (DIM / 32) + 577) {  // ---- foldv ----
    int fb = b - NNODES - (KA / 32) * (DIM / 32);
    int lane = tid & 63, wid = tid >> 6;
    int k = fb * 4 + wid;
    if (k <= 3 * DIM) {
      const float* row;
      if (k < DIM) row = w_root2 + (size_t)k * DIM;
      else if (k < 3 * DIM) row = w_rel2 + (size_t)(k - DIM) * DIM;
      else row = b2;
      float s = 0.f;
      for (int j = lane; j < DIM; j += 64) s += row[j] * clf_w[j];
#pragma unroll
      for (int off = 32; off > 0; off >>= 1) s += __shfl_down(s, off);
      if (lane == 0) v[k] = s + (k == 3 * DIM ? clf_b[0] : 0.f);
    }
  } else {  // ---- clear deg ----
    int cb = b - NNODES - (KA / 32) * (DIM / 32) - 577;
    int i = cb * 256 + tid;
    if (i < NBINS) deg[i] = 0;
  }
}

// ---------- CSR: hist -> scan -> scatter (parallel grids) ----------
__global__ __launch_bounds__(256) void hist_kernel(const int* __restrict__ dst,
                                                   const int* __restrict__ et,
                                                   int* __restrict__ deg) {
  int e = blockIdx.x * 256 + threadIdx.x;
  atomicAdd(&deg[et[e] * NNODES + dst[e]], 1);
}

// one block, wave-shuffle scan (2 barriers)
__global__ __launch_bounds__(1024) void scan_kernel(const int* __restrict__ deg,
                                                    int* __restrict__ offs,
                                                    int* __restrict__ cur) {
  __shared__ int wsum[16];
  int t = threadIdx.x, lane = t & 63, wid = t >> 6;
  int loc[5];
  int s = 0;
#pragma unroll
  for (int i = 0; i < 5; ++i) {
    int idx = t * 5 + i;
    loc[i] = s;
    s += (idx < NBINS) ? deg[idx] : 0;
  }
  int v = s;  // inclusive wave scan
#pragma unroll
  for (int off = 1; off < 64; off <<= 1) {
    int u = __shfl_up(v, off);
    if (lane >= off) v += u;
  }
  if (lane == 63) wsum[wid] = v;
  __syncthreads();
  if (wid == 0 && lane < 16) {
    int w = wsum[lane];
#pragma unroll
    for (int off = 1; off < 16; off <<= 1) {
      int u = __shfl_up(w, off);
      if (lane >= off) w += u;
    }
    wsum[lane] = w;
  }
  __syncthreads();
  int base = (wid == 0 ? 0 : wsum[wid - 1]) + (v - s);  // exclusive thread prefix
#pragma unroll
  for (int i = 0; i < 5; ++i) {
    int idx = t * 5 + i;
    if (idx < NBINS) {
      int val = base + loc[i];
      offs[idx] = val;
      cur[idx] = val;
    }
  }
  if (t == 1023) offs[NBINS] = wsum[15];
}

__global__ __launch_bounds__(256) void scatter_kernel(
    const int* __restrict__ srcv, const int* __restrict__ dst,
    const int* __restrict__ et, int* __restrict__ cur, int* __restrict__ perm) {
  int e = blockIdx.x * 256 + threadIdx.x;
  int bin = et[e] * NNODES + dst[e];
  int p = atomicAdd(&cur[bin], 1);
  perm[p] = srcv[e];
}

// ---------- per-bin mean gather (layer 1): writes A1 num-slices ----------
__global__ __launch_bounds__(192) void gather_kernel(const u16* __restrict__ A,
                                                     const int* __restrict__ offs,
                                                     const int* __restrict__ perm,
                                                     u16* __restrict__ Anum) {
  int bin = blockIdx.x;  // r*NNODES + d
  int r = bin / NNODES;
  int d = bin - r * NNODES;
  int beg = offs[bin], end = offs[bin + 1];
  int t = threadIdx.x;
  float a0 = 0.f, a1 = 0.f, a2 = 0.f, a3 = 0.f;
  for (int i = beg; i < end; ++i) {
    int s = perm[i];
    u16x4 v = *reinterpret_cast<const u16x4*>(&A[(size_t)s * KA + t * 4]);
    a0 += bf2f(v.x); a1 += bf2f(v.y); a2 += bf2f(v.z); a3 += bf2f(v.w);
  }
  float inv = (end > beg) ? 1.0f / (float)(end - beg) : 0.0f;
  u16x4 o;
  o.x = f2bf(a0 * inv); o.y = f2bf(a1 * inv); o.z = f2bf(a2 * inv); o.w = f2bf(a3 * inv);
  *reinterpret_cast<u16x4*>(&Anum[(size_t)d * KA + DIM + (size_t)r * DIM + t * 4]) = o;
}

// ---------- bf16 MFMA GEMM: out1[NPAD x 768] = A[NPAD x 2304] @ Bt^T + bias ----
// 64x64 tile, BK=64, 4 waves (2x2, 32x32 each), double-buffered LDS, 2-phase
// prefetch, XCD-swizzled 1D grid of 408. C is compact: ldc = DIM.
__global__ __launch_bounds__(256) void gemm_kernel(
    const u16* __restrict__ A, const u16* __restrict__ Bt,
    const float* __restrict__ bias, u16* __restrict__ C /* ldc = DIM */) {
  __shared__ u16 As[2][64 * BK];
  __shared__ u16 Bs[2][64 * BK];
  int wg = blockIdx.x;                  // 0..407, 408 = 8 XCDs * 51
  int swz = (wg & 7) * 51 + (wg >> 3);  // bijective: contiguous tiles per XCD
  int bm = swz / 12, bn = swz % 12;     // 34 x 12 tile grid
  int row0 = bm * 64, col0 = bn * 64;
  int tid = threadIdx.x;
  int lane = tid & 63, wid = tid >> 6;
  int wr = wid >> 1, wc = wid & 1;
  int l15 = lane & 15, l4 = lane >> 4;
  int sr = tid >> 3;  // staging row within 32-row chunk
  int sc = tid & 7;   // staging 16B slot
  f32x4 acc[2][2] = {};

#define STAGE(b, kbase)                                                         \
  {                                                                             \
    _Pragma("unroll") for (int h = 0; h < 2; ++h) {                             \
      int r = h * 32 + sr;                                                      \
      int kk = (sc ^ (r & 7)) * 8; /* pre-swizzled global source (rule #21) */  \
      gld16(&A[(size_t)(row0 + r) * KA + (kbase) + kk],                         \
            &As[b][h * 2048 + tid * 8]);                                        \
      gld16(&Bt[(size_t)(col0 + r) * KA + (kbase) + kk],                        \
            &Bs[b][h * 2048 + tid * 8]);                                        \
    }                                                                           \
  }

  STAGE(0, 0);
  __syncthreads();

  const int nt = KA / BK;  // 36
  for (int t = 0; t < nt; ++t) {
    int buf = t & 1;
    if (t + 1 < nt) STAGE(buf ^ 1, (t + 1) * BK);
    bf16x8 af[2][2], bg[2][2];
#pragma unroll
    for (int h = 0; h < 2; ++h) {
#pragma unroll
      for (int m = 0; m < 2; ++m) {
        int rl = wr * 32 + m * 16 + l15;
        int ck = (h * 4 + l4) ^ (rl & 7);
        af[h][m] = *reinterpret_cast<const bf16x8*>(&As[buf][rl * BK + ck * 8]);
        int cl = wc * 32 + m * 16 + l15;
        int ck2 = (h * 4 + l4) ^ (cl & 7);
        bg[h][m] = *reinterpret_cast<const bf16x8*>(&Bs[buf][cl * BK + ck2 * 8]);
      }
    }
#pragma unroll
    for (int h = 0; h < 2; ++h)
#pragma unroll
      for (int m = 0; m < 2; ++m)
#pragma unroll
        for (int n = 0; n < 2; ++n)
          acc[m][n] = __builtin_amdgcn_mfma_f32_16x16x32_bf16(af[h][m], bg[h][n],
                                                              acc[m][n], 0, 0, 0);
    __syncthreads();
  }
#undef STAGE

#pragma unroll
  for (int m = 0; m < 2; ++m) {
#pragma unroll
    for (int n = 0; n < 2; ++n) {
      int col = col0 + wc * 32 + n * 16 + l15;
      float b = bias[col];
#pragma unroll
      for (int q = 0; q < 4; ++q) {
        int row = row0 + wr * 32 + m * 16 + l4 * 4 + q;
        C[(size_t)row * DIM + col] = f2bf(acc[m][n][q] + b);
      }
    }
  }
}

// ---------- fused layer-2 + classifier for span rows ----------
// z = out1_span . v_root + sum_r mean(out1[src in bin r]) . v_r + c0
__global__ __launch_bounds__(192) void span_kernel(
    const u16* __restrict__ out1, const int* __restrict__ offs,
    const int* __restrict__ perm, const float* __restrict__ v,
    float* __restrict__ out) {
  int i = blockIdx.x;  // span idx 0..NPASS-1
  int t = threadIdx.x;
  // root path
  u16x4 a = *reinterpret_cast<const u16x4*>(&out1[(size_t)(SPAN0 + i) * DIM + t * 4]);
  float4 w = *reinterpret_cast<const float4*>(&v[t * 4]);
  float s = bf2f(a.x) * w.x + bf2f(a.y) * w.y + bf2f(a.z) * w.z + bf2f(a.w) * w.w;
  // relation paths
#pragma unroll
  for (int r = 0; r < NREL; ++r) {
    int bin = r * NNODES + SPAN0 + i;
    int beg = offs[bin], end = offs[bin + 1];
    if (end > beg) {
      float a0 = 0.f, a1 = 0.f, a2 = 0.f, a3 = 0.f;
      for (int e = beg; e < end; ++e) {
        int sr = perm[e];
        u16x4 x = *reinterpret_cast<const u16x4*>(&out1[(size_t)sr * DIM + t * 4]);
        a0 += bf2f(x.x); a1 += bf2f(x.y); a2 += bf2f(x.z); a3 += bf2f(x.w);
      }
      float4 wr = *reinterpret_cast<const float4*>(&v[DIM + r * DIM + t * 4]);
      s += (a0 * wr.x + a1 * wr.y + a2 * wr.z + a3 * wr.w) / (float)(end - beg);
    }
  }
#pragma unroll
  for (int off = 32; off > 0; off >>= 1) s += __shfl_down(s, off);
  __shared__ float red[3];
  if ((t & 63) == 0) red[t >> 6] = s;
  __syncthreads();
  if (t == 0) {
    float z = red[0] + red[1] + red[2] + v[3 * DIM];
    float sc = 1.0f / (1.0f + expf(-z));
    out[i] = expf(sc * 5.0f);  // exp(score / TAU), TAU = 0.2
  }
}

extern "C" void kernel_launch(void* const* d_in, const int* in_sizes, int n_in,
                              void* d_out, int out_size, void* d_ws, size_t ws_size,
                              hipStream_t stream) {
  const int* doc_ids = (const int*)d_in[0];
  const int* pass_ids = (const int*)d_in[1];
  const int* edge_index = (const int*)d_in[2];
  const int* etype = (const int*)d_in[3];
  const float* embed = (const float*)d_in[4];
  const float* w_root1 = (const float*)d_in[5];
  const float* w_rel1 = (const float*)d_in[6];
  const float* b1 = (const float*)d_in[7];
  const float* w_root2 = (const float*)d_in[8];
  const float* w_rel2 = (const float*)d_in[9];
  const float* b2 = (const float*)d_in[10];
  const float* clf_w = (const float*)d_in[11];
  const float* clf_b = (const float*)d_in[12];
  float* out = (float*)d_out;

  const int* src = edge_index;
  const int* dst = edge_index + NEDGES;

  u16* A1 = (u16*)d_ws;                        // NPAD * KA bf16
  u16* out1 = A1 + (size_t)NPAD * KA;          // NPAD * DIM bf16
  u16* Bt = out1 + (size_t)NPAD * DIM;         // DIM * KA bf16
  float* v = (float*)(Bt + (size_t)DIM * KA);  // 3*DIM + 1
  int* offs = (int*)(v + 3 * DIM + 1);         // NBINS + 1
  int* perm = offs + NBINS + 1;                // NEDGES
  int* deg = perm + NEDGES;                    // NBINS
  int* cur = deg + NBINS;                      // NBINS

  const int prep_blocks = NNODES + (KA / 32) * (DIM / 32) + 577 + 17;

  prep_kernel<<<prep_blocks, 256, 0, stream>>>(doc_ids, pass_ids, embed, w_root1,
                                               w_rel1, w_root2, w_rel2, b2, clf_w,
                                               clf_b, A1, Bt, v, deg);
  hist_kernel<<<NEDGES / 256, 256, 0, stream>>>(dst, etype, deg);
  scan_kernel<<<1, 1024, 0, stream>>>(deg, offs, cur);
  scatter_kernel<<<NEDGES / 256, 256, 0, stream>>>(src, dst, etype, cur, perm);
  gather_kernel<<<NBINS, 192, 0, stream>>>(A1, offs, perm, A1);
  gemm_kernel<<<408, 256, 0, stream>>>(A1, Bt, b1, out1);
  span_kernel<<<NPASS, 192, 0, stream>>>(out1, offs, perm, v, out);
}

// Round 7
// 42.189 us; speedup vs baseline: 2.4356x; 1.6796x over previous
//
#include <hip/hip_runtime.h>

#define NDOCS 64
#define NPASS 1024
#define TITLE_LEN 128
#define SEQ 256
#define NEDGES 32768
#define NNODES 2112   // NDOCS + 2*NPASS
#define DIM 768
#define SPAN_TOK 30522
#define NREL 2
#define NBINS (NREL * NNODES)  // 4224
#define SPAN0 (NNODES - NPASS)  // 1088

__device__ inline float wred(float s) {
#pragma unroll
  for (int off = 32; off > 0; off >>= 1) s += __shfl_down(s, off);
  return s;
}

// ---------- foldv: v[k] = row_k(Wcat2).clf_w (k<2304), v[2304]=b2.clf_w+clf_b
// blocks [577, 594): zero deg
__global__ __launch_bounds__(256) void foldv_kernel(
    const float* __restrict__ w_root2, const float* __restrict__ w_rel2,
    const float* __restrict__ b2, const float* __restrict__ clf_w,
    const float* __restrict__ clf_b, float* __restrict__ v,
    int* __restrict__ deg) {
  int b = blockIdx.x;
  if (b < 577) {
    int k = b * 4 + (threadIdx.x >> 6);
    int lane = threadIdx.x & 63;
    if (k > 3 * DIM) return;
    const float* row = (k < DIM) ? w_root2 + (size_t)k * DIM
                     : (k < 3 * DIM) ? w_rel2 + (size_t)(k - DIM) * DIM
                                     : b2;
    float s = 0.f;
    for (int j = lane; j < DIM; j += 64) s += row[j] * clf_w[j];
    s = wred(s);
    if (lane == 0) v[k] = s + (k == 3 * DIM ? clf_b[0] : 0.f);
  } else {
    int i = (b - 577) * 256 + threadIdx.x;
    if (i < NBINS) deg[i] = 0;
  }
}

// ---------- CSR: hist -> scan -> scatter ----------
__global__ __launch_bounds__(256) void hist_kernel(const int* __restrict__ dst,
                                                   const int* __restrict__ et,
                                                   int* __restrict__ deg) {
  int e = blockIdx.x * 256 + threadIdx.x;
  atomicAdd(&deg[et[e] * NNODES + dst[e]], 1);
}

// one block, wave-shuffle scan (2 barriers)
__global__ __launch_bounds__(1024) void scan_kernel(const int* __restrict__ deg,
                                                    int* __restrict__ offs,
                                                    int* __restrict__ cur) {
  __shared__ int wsum[16];
  int t = threadIdx.x, lane = t & 63, wid = t >> 6;
  int loc[5];
  int s = 0;
#pragma unroll
  for (int i = 0; i < 5; ++i) {
    int idx = t * 5 + i;
    loc[i] = s;
    s += (idx < NBINS) ? deg[idx] : 0;
  }
  int v = s;  // inclusive wave scan
#pragma unroll
  for (int off = 1; off < 64; off <<= 1) {
    int u = __shfl_up(v, off);
    if (lane >= off) v += u;
  }
  if (lane == 63) wsum[wid] = v;
  __syncthreads();
  if (wid == 0 && lane < 16) {
    int w = wsum[lane];
#pragma unroll
    for (int off = 1; off < 16; off <<= 1) {
      int u = __shfl_up(w, off);
      if (lane >= off) w += u;
    }
    wsum[lane] = w;
  }
  __syncthreads();
  int base = (wid == 0 ? 0 : wsum[wid - 1]) + (v - s);  // exclusive thread prefix
#pragma unroll
  for (int i = 0; i < 5; ++i) {
    int idx = t * 5 + i;
    if (idx < NBINS) {
      int val = base + loc[i];
      offs[idx] = val;
      cur[idx] = val;
    }
  }
  if (t == 1023) offs[NBINS] = wsum[15];
}

__global__ __launch_bounds__(256) void scatter_kernel(
    const int* __restrict__ srcv, const int* __restrict__ dst,
    const int* __restrict__ et, int* __restrict__ cur, int* __restrict__ perm) {
  int e = blockIdx.x * 256 + threadIdx.x;
  int bin = et[e] * NNODES + dst[e];
  int p = atomicAdd(&cur[bin], 1);
  perm[p] = srcv[e];
}

// ---------- foldU: U4[k] = {row_k(Wcat1).v_root, .v_0, .v_1}; U4[2304] = d_j --
__global__ __launch_bounds__(256) void foldu_kernel(
    const float* __restrict__ w_root1, const float* __restrict__ w_rel1,
    const float* __restrict__ b1, const float* __restrict__ v,
    float4* __restrict__ U4) {
  int k = blockIdx.x * 4 + (threadIdx.x >> 6);
  int lane = threadIdx.x & 63;
  if (k > 3 * DIM) return;
  const float* row = (k < DIM) ? w_root1 + (size_t)k * DIM
                   : (k < 3 * DIM) ? w_rel1 + (size_t)(k - DIM) * DIM
                                   : b1;
  float s0 = 0.f, s1 = 0.f, s2 = 0.f;
  for (int j = lane; j < DIM; j += 64) {
    float r = row[j];
    s0 += r * v[j];
    s1 += r * v[DIM + j];
    s2 += r * v[2 * DIM + j];
  }
  s0 = wred(s0); s1 = wred(s1); s2 = wred(s2);
  if (lane == 0) U4[k] = make_float4(s0, s1, s2, 0.f);
}

// ---------- T: per node m, T[m][a][j] = x0[m] . U[a*768..][j] (9 scalars) ----
__global__ __launch_bounds__(256) void t_kernel(
    const int* __restrict__ doc_ids, const int* __restrict__ pass_ids,
    const float* __restrict__ embed, const float4* __restrict__ U4,
    float4* __restrict__ Tq) {
  int m = blockIdx.x * 4 + (threadIdx.x >> 6);
  int lane = threadIdx.x & 63;
  if (m >= NNODES) return;
  int tok = (m < NDOCS) ? doc_ids[m * TITLE_LEN]
          : (m < NDOCS + NPASS) ? pass_ids[(m - NDOCS) * SEQ]
                                : SPAN_TOK;
  const float* e = embed + (size_t)tok * DIM;
  float s[9] = {};
  for (int j = lane; j < DIM; j += 64) {
    float ev = e[j];
    float4 u0 = U4[j], u1 = U4[DIM + j], u2 = U4[2 * DIM + j];
    s[0] += ev * u0.x; s[1] += ev * u0.y; s[2] += ev * u0.z;
    s[3] += ev * u1.x; s[4] += ev * u1.y; s[5] += ev * u1.z;
    s[6] += ev * u2.x; s[7] += ev * u2.y; s[8] += ev * u2.z;
  }
#pragma unroll
  for (int a = 0; a < 9; ++a) s[a] = wred(s[a]);
  if (lane == 0) {
    Tq[m * 4 + 0] = make_float4(s[0], s[1], s[2], 0.f);
    Tq[m * 4 + 1] = make_float4(s[3], s[4], s[5], 0.f);
    Tq[m * 4 + 2] = make_float4(s[6], s[7], s[8], 0.f);
  }
}

// ---------- p: p_j[m] = T[m][0][j] + mean_b0 T[src][1][j] + mean_b1 T[src][2][j] + d_j
__global__ __launch_bounds__(256) void p_kernel(
    const float4* __restrict__ Tq, const float4* __restrict__ U4,
    const int* __restrict__ offs, const int* __restrict__ perm,
    float4* __restrict__ P4) {
  int m = blockIdx.x * 4 + (threadIdx.x >> 6);
  int lane = threadIdx.x & 63;
  if (m >= NNODES) return;
  int b0 = offs[m], e0 = offs[m + 1];
  int b1 = offs[NNODES + m], e1 = offs[NNODES + m + 1];
  float a0 = 0.f, a1 = 0.f, a2 = 0.f, c0 = 0.f, c1 = 0.f, c2 = 0.f;
  for (int i = b0 + lane; i < e0; i += 64) {
    float4 t = Tq[perm[i] * 4 + 1];
    a0 += t.x; a1 += t.y; a2 += t.z;
  }
  for (int i = b1 + lane; i < e1; i += 64) {
    float4 t = Tq[perm[i] * 4 + 2];
    c0 += t.x; c1 += t.y; c2 += t.z;
  }
  a0 = wred(a0); a1 = wred(a1); a2 = wred(a2);
  c0 = wred(c0); c1 = wred(c1); c2 = wred(c2);
  if (lane == 0) {
    float i0 = (e0 > b0) ? 1.f / (float)(e0 - b0) : 0.f;
    float i1 = (e1 > b1) ? 1.f / (float)(e1 - b1) : 0.f;
    float4 t0 = Tq[m * 4];
    float4 D = U4[3 * DIM];
    P4[m] = make_float4(t0.x + a0 * i0 + c0 * i1 + D.x,
                        t0.y + a1 * i0 + c1 * i1 + D.y,
                        t0.z + a2 * i0 + c2 * i1 + D.z, 0.f);
  }
}

// ---------- z: span rows -> out ----------
__global__ __launch_bounds__(256) void z_kernel(
    const float4* __restrict__ P4, const int* __restrict__ offs,
    const int* __restrict__ perm, const float* __restrict__ v,
    float* __restrict__ out) {
  int i = blockIdx.x * 4 + (threadIdx.x >> 6);
  int lane = threadIdx.x & 63;
  int n = SPAN0 + i;
  int b0 = offs[n], e0 = offs[n + 1];
  int b1 = offs[NNODES + n], e1 = offs[NNODES + n + 1];
  float s0 = 0.f, s1 = 0.f;
  for (int e = b0 + lane; e < e0; e += 64) s0 += P4[perm[e]].y;
  for (int e = b1 + lane; e < e1; e += 64) s1 += P4[perm[e]].z;
  s0 = wred(s0); s1 = wred(s1);
  if (lane == 0) {
    float i0 = (e0 > b0) ? 1.f / (float)(e0 - b0) : 0.f;
    float i1 = (e1 > b1) ? 1.f / (float)(e1 - b1) : 0.f;
    float z = P4[n].x + s0 * i0 + s1 * i1 + v[3 * DIM];
    float sc = 1.f / (1.f + expf(-z));
    out[i] = expf(sc * 5.f);  // exp(score / TAU), TAU = 0.2
  }
}

extern "C" void kernel_launch(void* const* d_in, const int* in_sizes, int n_in,
                              void* d_out, int out_size, void* d_ws, size_t ws_size,
                              hipStream_t stream) {
  const int* doc_ids = (const int*)d_in[0];
  const int* pass_ids = (const int*)d_in[1];
  const int* edge_index = (const int*)d_in[2];
  const int* etype = (const int*)d_in[3];
  const float* embed = (const float*)d_in[4];
  const float* w_root1 = (const float*)d_in[5];
  const float* w_rel1 = (const float*)d_in[6];
  const float* b1 = (const float*)d_in[7];
  const float* w_root2 = (const float*)d_in[8];
  const float* w_rel2 = (const float*)d_in[9];
  const float* b2 = (const float*)d_in[10];
  const float* clf_w = (const float*)d_in[11];
  const float* clf_b = (const float*)d_in[12];
  float* out = (float*)d_out;

  const int* src = edge_index;
  const int* dst = edge_index + NEDGES;

  float4* U4 = (float4*)d_ws;              // 2305
  float4* Tq = U4 + (3 * DIM + 1);         // NNODES*4
  float4* P4 = Tq + (size_t)NNODES * 4;    // NNODES
  float* v = (float*)(P4 + NNODES);        // 2305
  int* offs = (int*)(v + 3 * DIM + 1);     // NBINS + 1
  int* perm = offs + NBINS + 1;            // NEDGES
  int* deg = perm + NEDGES;                // NBINS
  int* cur = deg + NBINS;                  // NBINS

  foldv_kernel<<<577 + 17, 256, 0, stream>>>(w_root2, w_rel2, b2, clf_w, clf_b,
                                             v, deg);
  hist_kernel<<<NEDGES / 256, 256, 0, stream>>>(dst, etype, deg);
  scan_kernel<<<1, 1024, 0, stream>>>(deg, offs, cur);
  scatter_kernel<<<NEDGES / 256, 256, 0, stream>>>(src, dst, etype, cur, perm);
  foldu_kernel<<<577, 256, 0, stream>>>(w_root1, w_rel1, b1, v, U4);
  t_kernel<<<NNODES / 4, 256, 0, stream>>>(doc_ids, pass_ids, embed, U4, Tq);
  p_kernel<<<NNODES / 4, 256, 0, stream>>>(Tq, U4, offs, perm, P4);
  z_kernel<<<NPASS / 4, 256, 0, stream>>>(P4, offs, perm, v, out);
}

// Round 8
// 37.502 us; speedup vs baseline: 2.7401x; 1.1250x over previous
//
#include <hip/hip_runtime.h>

#define NDOCS 64
#define NPASS 1024
#define TITLE_LEN 128
#define SEQ 256
#define NEDGES 32768
#define NNODES 2112   // NDOCS + 2*NPASS
#define DIM 768
#define SPAN_TOK 30522
#define NREL 2
#define NBINS (NREL * NNODES)   // 4224
#define SPAN0 (NNODES - NPASS)  // 1088
// contiguous clear region: accP | zacc | deg
#define CLRWORDS (NNODES * 6 + NPASS * 2 + NBINS)  // 18944 = 74 * 256

__device__ inline float wred(float s) {
#pragma unroll
  for (int off = 32; off > 0; off >>= 1) s += __shfl_down(s, off);
  return s;
}
__device__ inline float dot4(float4 a, float4 b) {
  return a.x * b.x + a.y * b.y + a.z * b.z + a.w * b.w;
}

// ---------- K1: foldv (v = Wcat2 . clf_w; v[2304] = b2.clf_w + clf_b) + clear
__global__ __launch_bounds__(256) void foldv_kernel(
    const float* __restrict__ w_root2, const float* __restrict__ w_rel2,
    const float* __restrict__ b2, const float* __restrict__ clf_w,
    const float* __restrict__ clf_b, float* __restrict__ v,
    int* __restrict__ clrbase) {
  int b = blockIdx.x;
  if (b < 577) {
    int k = b * 4 + (threadIdx.x >> 6);
    int lane = threadIdx.x & 63;
    if (k > 3 * DIM) return;
    const float* row = (k < DIM) ? w_root2 + (size_t)k * DIM
                     : (k < 3 * DIM) ? w_rel2 + (size_t)(k - DIM) * DIM
                                     : b2;
    const float4* r4 = (const float4*)row;
    const float4* w4 = (const float4*)clf_w;
    float s = 0.f;
#pragma unroll
    for (int i = 0; i < 3; ++i) {
      int j = lane + i * 64;
      s += dot4(r4[j], w4[j]);
    }
    s = wred(s);
    if (lane == 0) v[k] = s + (k == 3 * DIM ? clf_b[0] : 0.f);
  } else {
    int i = (b - 577) * 256 + threadIdx.x;
    if (i < CLRWORDS) clrbase[i] = 0;
  }
}

// ---------- K2: foldu (U4[k] = {row_k(Wcat1).v0, .v1, .v2}; U4[2304]=d) + hist
__global__ __launch_bounds__(256) void foldu_hist_kernel(
    const float* __restrict__ w_root1, const float* __restrict__ w_rel1,
    const float* __restrict__ b1, const float* __restrict__ v,
    float4* __restrict__ U4, const int* __restrict__ dst,
    const int* __restrict__ et, int* __restrict__ deg) {
  int b = blockIdx.x;
  if (b < 577) {
    int k = b * 4 + (threadIdx.x >> 6);
    int lane = threadIdx.x & 63;
    if (k > 3 * DIM) return;
    const float* row = (k < DIM) ? w_root1 + (size_t)k * DIM
                     : (k < 3 * DIM) ? w_rel1 + (size_t)(k - DIM) * DIM
                                     : b1;
    const float4* r4 = (const float4*)row;
    const float4* v0 = (const float4*)v;
    const float4* v1 = (const float4*)(v + DIM);
    const float4* v2 = (const float4*)(v + 2 * DIM);
    float s0 = 0.f, s1 = 0.f, s2 = 0.f;
#pragma unroll
    for (int i = 0; i < 3; ++i) {
      int j = lane + i * 64;
      float4 r = r4[j];
      s0 += dot4(r, v0[j]);
      s1 += dot4(r, v1[j]);
      s2 += dot4(r, v2[j]);
    }
    s0 = wred(s0); s1 = wred(s1); s2 = wred(s2);
    if (lane == 0) U4[k] = make_float4(s0, s1, s2, 0.f);
  } else {
    int e = (b - 577) * 256 + threadIdx.x;  // 128 blocks cover 32768 edges
    atomicAdd(&deg[et[e] * NNODES + dst[e]], 1);
  }
}

// ---------- K3: T[m][a][j] = x0[m] . U_a[:,j]  (9 scalars per node) ----------
__global__ __launch_bounds__(256) void t_kernel(
    const int* __restrict__ doc_ids, const int* __restrict__ pass_ids,
    const float* __restrict__ embed, const float4* __restrict__ U4,
    float4* __restrict__ Tq) {
  int m = blockIdx.x * 4 + (threadIdx.x >> 6);
  int lane = threadIdx.x & 63;
  int tok = (m < NDOCS) ? doc_ids[m * TITLE_LEN]
          : (m < NDOCS + NPASS) ? pass_ids[(m - NDOCS) * SEQ]
                                : SPAN_TOK;
  const float4* e4 = (const float4*)(embed + (size_t)tok * DIM);
  float s[9] = {};
#pragma unroll
  for (int i = 0; i < 3; ++i) {
    int j = lane + i * 64;  // float4 index; k = 4j..4j+3
    float4 ev = e4[j];
#pragma unroll
    for (int q = 0; q < 4; ++q) {
      int k = j * 4 + q;
      float e1 = (q == 0) ? ev.x : (q == 1) ? ev.y : (q == 2) ? ev.z : ev.w;
      float4 u0 = U4[k], u1 = U4[DIM + k], u2 = U4[2 * DIM + k];
      s[0] += e1 * u0.x; s[1] += e1 * u0.y; s[2] += e1 * u0.z;
      s[3] += e1 * u1.x; s[4] += e1 * u1.y; s[5] += e1 * u1.z;
      s[6] += e1 * u2.x; s[7] += e1 * u2.y; s[8] += e1 * u2.z;
    }
  }
#pragma unroll
  for (int a = 0; a < 9; ++a) s[a] = wred(s[a]);
  if (lane == 0) {
    Tq[m * 4 + 0] = make_float4(s[0], s[1], s[2], 0.f);
    Tq[m * 4 + 1] = make_float4(s[3], s[4], s[5], 0.f);
    Tq[m * 4 + 2] = make_float4(s[6], s[7], s[8], 0.f);
  }
}

// ---------- K4: accP[d][j][r] += T[src][1+r][j] (edge-parallel) ----------
__global__ __launch_bounds__(256) void pacc_kernel(
    const int* __restrict__ src, const int* __restrict__ dst,
    const int* __restrict__ et, const float4* __restrict__ Tq,
    float* __restrict__ accP) {
  int e = blockIdx.x * 256 + threadIdx.x;
  int s = src[e], d = dst[e], r = et[e];
  float4 t = Tq[s * 4 + 1 + r];
  atomicAdd(&accP[d * 6 + 0 + r], t.x);  // j=0
  atomicAdd(&accP[d * 6 + 2 + r], t.y);  // j=1
  atomicAdd(&accP[d * 6 + 4 + r], t.z);  // j=2
}

// ---------- K5: zacc[d][r] += P[src][1+r] computed on the fly ----------
__global__ __launch_bounds__(256) void zacc_kernel(
    const int* __restrict__ src, const int* __restrict__ dst,
    const int* __restrict__ et, const float4* __restrict__ Tq,
    const float* __restrict__ accP, const int* __restrict__ deg,
    const float4* __restrict__ U4, float* __restrict__ zacc) {
  int e = blockIdx.x * 256 + threadIdx.x;
  int d = dst[e];
  if (d < SPAN0) return;
  int s = src[e], r = et[e];
  int j = 1 + r;  // component of P
  float i0 = 1.f / fmaxf((float)deg[s], 1.f);
  float i1 = 1.f / fmaxf((float)deg[NNODES + s], 1.f);
  float t0j = ((const float*)(Tq + (size_t)s * 4))[j];
  float a0 = accP[s * 6 + j * 2 + 0];
  float a1 = accP[s * 6 + j * 2 + 1];
  float dj = ((const float*)(U4 + 3 * DIM))[j];
  float P = t0j + a0 * i0 + a1 * i1 + dj;
  atomicAdd(&zacc[(d - SPAN0) * 2 + r], P);
}

// ---------- K6: out[i] = exp(sigmoid(z)/TAU) ----------
__global__ __launch_bounds__(256) void final_kernel(
    const float4* __restrict__ Tq, const float* __restrict__ accP,
    const int* __restrict__ deg, const float* __restrict__ zacc,
    const float4* __restrict__ U4, const float* __restrict__ v,
    float* __restrict__ out) {
  int i = blockIdx.x * 256 + threadIdx.x;
  if (i >= NPASS) return;
  int n = SPAN0 + i;
  float i0 = 1.f / fmaxf((float)deg[n], 1.f);
  float i1 = 1.f / fmaxf((float)deg[NNODES + n], 1.f);
  // P[n][0]
  float P0 = Tq[n * 4].x + accP[n * 6 + 0] * i0 + accP[n * 6 + 1] * i1 +
             U4[3 * DIM].x;
  float z = P0 + zacc[i * 2 + 0] * i0 + zacc[i * 2 + 1] * i1 + v[3 * DIM];
  float sc = 1.f / (1.f + expf(-z));
  out[i] = expf(sc * 5.f);  // exp(score / TAU), TAU = 0.2
}

extern "C" void kernel_launch(void* const* d_in, const int* in_sizes, int n_in,
                              void* d_out, int out_size, void* d_ws, size_t ws_size,
                              hipStream_t stream) {
  const int* doc_ids = (const int*)d_in[0];
  const int* pass_ids = (const int*)d_in[1];
  const int* edge_index = (const int*)d_in[2];
  const int* etype = (const int*)d_in[3];
  const float* embed = (const float*)d_in[4];
  const float* w_root1 = (const float*)d_in[5];
  const float* w_rel1 = (const float*)d_in[6];
  const float* b1 = (const float*)d_in[7];
  const float* w_root2 = (const float*)d_in[8];
  const float* w_rel2 = (const float*)d_in[9];
  const float* b2 = (const float*)d_in[10];
  const float* clf_w = (const float*)d_in[11];
  const float* clf_b = (const float*)d_in[12];
  float* out = (float*)d_out;

  const int* src = edge_index;
  const int* dst = edge_index + NEDGES;

  float4* U4 = (float4*)d_ws;                 // 2305 float4
  float4* Tq = U4 + (3 * DIM + 1);            // NNODES*4 float4
  float* v = (float*)(Tq + (size_t)NNODES * 4);  // 2305 floats
  float* accP = v + (3 * DIM + 1);            // NNODES*6  (clear region start)
  float* zacc = accP + NNODES * 6;            // NPASS*2
  int* deg = (int*)(zacc + NPASS * 2);        // NBINS

  foldv_kernel<<<577 + 74, 256, 0, stream>>>(w_root2, w_rel2, b2, clf_w, clf_b,
                                             v, (int*)accP);
  foldu_hist_kernel<<<577 + 128, 256, 0, stream>>>(w_root1, w_rel1, b1, v, U4,
                                                   dst, etype, deg);
  t_kernel<<<NNODES / 4, 256, 0, stream>>>(doc_ids, pass_ids, embed, U4, Tq);
  pacc_kernel<<<NEDGES / 256, 256, 0, stream>>>(src, dst, etype, Tq, accP);
  zacc_kernel<<<NEDGES / 256, 256, 0, stream>>>(src, dst, etype, Tq, accP, deg,
                                                U4, zacc);
  final_kernel<<<NPASS / 256, 256, 0, stream>>>(Tq, accP, deg, zacc, U4, v, out);
}